// Round 5
// baseline (376.688 us; speedup 1.0000x reference)
//
#include <hip/hip_runtime.h>
#include <stdint.h>
#include <stddef.h>

#define E_TOTAL 1000000
#define N_NODES 100000
#define FD      128
#define ETILE   64
#define NTILES  (E_TOTAL / ETILE)   // 15625 exactly
#define GRID    2048

typedef __attribute__((ext_vector_type(8))) short short8;
typedef __attribute__((ext_vector_type(4))) float f32x4;

// round-to-nearest-even fp32 -> bf16 (bit pattern in a short)
__device__ __forceinline__ short f2bf(float f) {
  union { float f; unsigned u; } v; v.f = f;
  unsigned r = (v.u + 0x7FFFu + ((v.u >> 16) & 1u)) >> 16;
  return (short)(r & 0xFFFFu);
}

// XOR-swizzled index helpers (short-granular; byte-swizzle bits 4-6 == short bits 3-5).
// H0: logical [64][256] bf16. chunk c8 is a multiple of 8 shorts -> b128 stays 16B-aligned.
__device__ __forceinline__ int h0idx(int row, int c8) {
  return row * 256 + (c8 ^ ((row & 7) << 3));
}
// H1: logical [64][64] bf16. slot = (row>>1)&7 spreads the 128B rows across banks.
__device__ __forceinline__ int h1idx(int row, int c) {
  return row * 64 + (c ^ (((row >> 1) & 7) << 3));
}

__global__ __launch_bounds__(256, 4)   // force VGPR<=128: 4 blocks/CU needs 16 waves/CU
void linkpred_kernel(const float* __restrict__ x,
                     const int* __restrict__ ei,       // [2][E_TOTAL], int32
                     const float* __restrict__ W1, const float* __restrict__ b1,
                     const float* __restrict__ A1,
                     const float* __restrict__ W2, const float* __restrict__ b2,
                     const float* __restrict__ A2,
                     const float* __restrict__ W3, const float* __restrict__ b3,
                     const float* __restrict__ A3,
                     const float* __restrict__ Wf, const float* __restrict__ bfp,
                     float* __restrict__ out)
{
  // LDS diet for 4 blocks/CU: 32768 + 8192 = 40960 B exactly (160K/4).
  __shared__ __align__(16) short H0[ETILE * 256];   // concat(x[src],x[dst]) bf16, XOR-swizzled
  __shared__ __align__(16) short H12[ETILE * 64];   // union: H1 (swizzled [64][64]) then H2 ([64][40] padded)

  const int tid  = threadIdx.x;
  const int w    = tid >> 6;     // wave 0..3
  const int lane = tid & 63;
  const int col  = lane & 15;
  const int quad = lane >> 4;    // 0..3

  // ---------------- register-resident weight B-fragments (88 VGPRs) ----------------
  // Layer1: Wcat1 = [W1 | A1] (K=256, N=128). Wave w owns cols {16w..} and {64+16w..}.
  short8 B1f[2][8];
  for (int p = 0; p < 2; ++p) {
    const int n = 16 * (w + 4 * p) + col;                     // 0..127
    const float* src = (p == 0) ? (W1 + n) : (A1 + (n - 64));
    for (int kt = 0; kt < 8; ++kt) {
      short8 f;
      for (int j = 0; j < 8; ++j)
        f[j] = f2bf(src[(kt * 32 + quad * 8 + j) * 64]);
      B1f[p][kt] = f;
    }
  }
  // Layer2: Wcat2 = [W2 | A2] (K=64, N=64). Wave w owns col pair {16*(w&1), 32+16*(w&1)}.
  short8 B2f[2][2];
  for (int p = 0; p < 2; ++p) {
    const int n = 16 * ((w & 1) + 2 * p) + col;               // 0..63
    const float* src = (p == 0) ? (W2 + n) : (A2 + (n - 32));
    for (int kt = 0; kt < 2; ++kt) {
      short8 f;
      for (int j = 0; j < 8; ++j)
        f[j] = f2bf(src[(kt * 32 + quad * 8 + j) * 32]);
      B2f[p][kt] = f;
    }
  }
  // Layer3: Wcat3 = [W3 | A3] (K=32, N=32). All waves own col pair {0,16}.
  short8 B3f[2];
  for (int p = 0; p < 2; ++p) {
    const int n = 16 * p + col;                               // 0..31
    const float* src = (p == 0) ? (W3 + n) : (A3 + (n - 16));
    short8 f;
    for (int j = 0; j < 8; ++j)
      f[j] = f2bf(src[(quad * 8 + j) * 16]);
    B3f[p] = f;
  }
  const float b1v = b1[16 * w + col];
  const float b2v = b2[16 * (w & 1) + col];
  const float b3v = b3[col];
  const float bfv = bfp[0];
  const float Wfv = Wf[col];
  const f32x4 zero = {0.f, 0.f, 0.f, 0.f};

  for (int tile = blockIdx.x; tile < NTILES; tile += gridDim.x) {
    const int e0 = tile * ETILE;

    // ---- gather: wave w owns half-rows h = w*32 + it*4 + quad (it 0..7).
    // 16 lanes (quad-group) read one 512B fp32 row cooperatively (32B/lane).
    // Two batches of 4 keep nd[]+transients small (VGPR peak ~120 <= 128: no scratch).
    for (int b = 0; b < 2; ++b) {
      int nd[4];
#pragma unroll
      for (int it = 0; it < 4; ++it) {
        const int h = w * 32 + (b * 4 + it) * 4 + quad;
        nd[it] = ei[(h & 1) * E_TOTAL + e0 + (h >> 1)];   // 16-lane broadcast, L2-hot
      }
#pragma unroll
      for (int it = 0; it < 4; ++it) {
        const int h = w * 32 + (b * 4 + it) * 4 + quad;
        const float4* s4 = ((const float4*)(x + (size_t)nd[it] * FD)) + col * 2;
        float4 va = s4[0];
        float4 vb = s4[1];
        short8 s;
        s[0] = f2bf(va.x); s[1] = f2bf(va.y); s[2] = f2bf(va.z); s[3] = f2bf(va.w);
        s[4] = f2bf(vb.x); s[5] = f2bf(vb.y); s[6] = f2bf(vb.z); s[7] = f2bf(vb.w);
        *(short8*)&H0[h0idx(h >> 1, (h & 1) * 128 + col * 8)] = s;
      }
    }
    __syncthreads();                                 // B1: H0 ready

    // ---- layer 1: [64x256] @ [256x128], wave w -> all M, col pair {w, w+4} ----
    for (int mt = 0; mt < 4; ++mt) {
      f32x4 a0 = zero, a1 = zero;
      for (int kt = 0; kt < 8; ++kt) {
        short8 a = *(const short8*)&H0[h0idx(mt * 16 + col, kt * 32 + quad * 8)];
        a0 = __builtin_amdgcn_mfma_f32_16x16x32_bf16(a, B1f[0][kt], a0, 0, 0, 0);
        a1 = __builtin_amdgcn_mfma_f32_16x16x32_bf16(a, B1f[1][kt], a1, 0, 0, 0);
      }
      for (int r = 0; r < 4; ++r) {
        float o = fmaxf(a0[r] + b1v, 0.f);          // relu(h@W1 + b1)
        float h = fmaxf(o + a1[r], 0.f);            // relu(out + h@A1)
        H12[h1idx(mt * 16 + quad * 4 + r, 16 * w + col)] = f2bf(h);
      }
    }
    __syncthreads();                                 // B2: H1 ready

    // ---- layer 2 compute: [64x64] @ [64x64], waves split M in halves ----
    f32x4 c2w[2], c2a[2];
    c2w[0] = zero; c2w[1] = zero; c2a[0] = zero; c2a[1] = zero;
    for (int mi = 0; mi < 2; ++mi) {
      const int m = (2 * (w >> 1) + mi) * 16 + col;
      for (int kt = 0; kt < 2; ++kt) {
        short8 a = *(const short8*)&H12[h1idx(m, kt * 32 + quad * 8)];
        c2w[mi] = __builtin_amdgcn_mfma_f32_16x16x32_bf16(a, B2f[0][kt], c2w[mi], 0, 0, 0);
        c2a[mi] = __builtin_amdgcn_mfma_f32_16x16x32_bf16(a, B2f[1][kt], c2a[mi], 0, 0, 0);
      }
    }
    __syncthreads();                                 // B3: all H1 reads done (union hazard)

    // ---- layer 2 writeback: H2 ([64][40] padded) overlays H1's buffer ----
    for (int mi = 0; mi < 2; ++mi)
      for (int r = 0; r < 4; ++r) {
        float o = fmaxf(c2w[mi][r] + b2v, 0.f);
        float h = fmaxf(o + c2a[mi][r], 0.f);
        H12[((2 * (w >> 1) + mi) * 16 + quad * 4 + r) * 40 + 16 * (w & 1) + col] = f2bf(h);
      }
    __syncthreads();                                 // B4: H2 ready

    // ---- layer 3: [64x32] @ [32x32], wave w -> M-tile w ----
    f32x4 acc3[2];
    acc3[0] = zero; acc3[1] = zero;
    {
      short8 a = *(const short8*)&H12[(w * 16 + col) * 40 + quad * 8];
      acc3[0] = __builtin_amdgcn_mfma_f32_16x16x32_bf16(a, B3f[0], acc3[0], 0, 0, 0);
      acc3[1] = __builtin_amdgcn_mfma_f32_16x16x32_bf16(a, B3f[1], acc3[1], 0, 0, 0);
    }

    // ---- final: 16-dot via width-16 shfl butterfly, sigmoid, store ----
    // lane (quad,col) reg r holds h3[edge = w*16 + quad*4 + r][feature col]
#pragma unroll
    for (int r = 0; r < 4; ++r) {
      float o = fmaxf(acc3[0][r] + b3v, 0.f);
      float h = fmaxf(o + acc3[1][r], 0.f);
      float t = h * Wfv;
      t += __shfl_xor(t, 1, 16);
      t += __shfl_xor(t, 2, 16);
      t += __shfl_xor(t, 4, 16);
      t += __shfl_xor(t, 8, 16);
      if (col == r) {
        float s = bfv + t;
        out[e0 + w * 16 + quad * 4 + r] = 1.0f / (1.0f + __expf(-s));
      }
    }
    // loop hazard audit: next-iter gather writes H0 — every wave passed B2 (last
    // H0 reads are in layer 1, before B2). Next-iter H1 writes sit behind next B1;
    // this iter's H12 reads (layer 3) complete before that barrier. Safe.
  }
}

extern "C" void kernel_launch(void* const* d_in, const int* in_sizes, int n_in,
                              void* d_out, int out_size, void* d_ws, size_t ws_size,
                              hipStream_t stream) {
  const float* x   = (const float*)d_in[0];
  const int*   ei  = (const int*)d_in[1];
  const float* W1  = (const float*)d_in[2];
  const float* b1  = (const float*)d_in[3];
  const float* A1  = (const float*)d_in[4];
  const float* W2  = (const float*)d_in[5];
  const float* b2  = (const float*)d_in[6];
  const float* A2  = (const float*)d_in[7];
  const float* W3  = (const float*)d_in[8];
  const float* b3  = (const float*)d_in[9];
  const float* A3  = (const float*)d_in[10];
  const float* Wf  = (const float*)d_in[11];
  const float* bfp = (const float*)d_in[12];

  hipLaunchKernelGGL(linkpred_kernel, dim3(GRID), dim3(256), 0, stream,
                     x, ei, W1, b1, A1, W2, b2, A2, W3, b3, A3, Wf, bfp,
                     (float*)d_out);
}

// Round 8
// 272.912 us; speedup vs baseline: 1.3803x; 1.3803x over previous
//
#include <hip/hip_runtime.h>
#include <stdint.h>
#include <stddef.h>

#define E_TOTAL 1000000
#define N_NODES 100000
#define FD      128
#define ETILE   64
#define NTILES  (E_TOTAL / ETILE)   // 15625 exactly
#define GRID    2048

typedef __attribute__((ext_vector_type(8))) short short8;
typedef __attribute__((ext_vector_type(4))) float f32x4;

// round-to-nearest-even fp32 -> bf16 (bit pattern in a short)
__device__ __forceinline__ short f2bf(float f) {
  union { float f; unsigned u; } v; v.f = f;
  unsigned r = (v.u + 0x7FFFu + ((v.u >> 16) & 1u)) >> 16;
  return (short)(r & 0xFFFFu);
}

// XOR-swizzled index helpers (short-granular; byte-swizzle bits 4-6 == short bits 3-5).
// H0: logical [64][256] bf16. chunk c8 is a multiple of 8 shorts -> b128 stays 16B-aligned.
__device__ __forceinline__ int h0idx(int row, int c8) {
  return row * 256 + (c8 ^ ((row & 7) << 3));
}
// H1: logical [64][64] bf16. slot = (row>>1)&7 spreads the 128B rows across banks.
__device__ __forceinline__ int h1idx(int row, int c) {
  return row * 64 + (c ^ (((row >> 1) & 7) << 3));
}

// (256,2): round-5's (256,4) made the allocator target 64 VGPR -> 88 weight regs
// spilled to scratch (FETCH +337MB, WRITE +137MB, L 7.6->19.3us/tile). With (256,2)
// this body compiles to ~100-110 VGPR (rounds 0-2), so 512/110 -> 4 waves/EU and
// LDS 40960B -> 4 blocks/CU: same residency goal, spill-free.
__global__ __launch_bounds__(256, 2)
void linkpred_kernel(const float* __restrict__ x,
                     const int* __restrict__ ei,       // [2][E_TOTAL], int32
                     const float* __restrict__ W1, const float* __restrict__ b1,
                     const float* __restrict__ A1,
                     const float* __restrict__ W2, const float* __restrict__ b2,
                     const float* __restrict__ A2,
                     const float* __restrict__ W3, const float* __restrict__ b3,
                     const float* __restrict__ A3,
                     const float* __restrict__ Wf, const float* __restrict__ bfp,
                     float* __restrict__ out)
{
  // LDS diet for 4 blocks/CU: 32768 + 8192 = 40960 B exactly (160K/4).
  __shared__ __align__(16) short H0[ETILE * 256];   // concat(x[src],x[dst]) bf16, XOR-swizzled
  __shared__ __align__(16) short H12[ETILE * 64];   // union: H1 (swizzled [64][64]) then H2 ([64][40] padded)

  const int tid  = threadIdx.x;
  const int w    = tid >> 6;     // wave 0..3
  const int lane = tid & 63;
  const int col  = lane & 15;
  const int quad = lane >> 4;    // 0..3

  // ---------------- register-resident weight B-fragments (88 VGPRs) ----------------
  // Layer1: Wcat1 = [W1 | A1] (K=256, N=128). Wave w owns cols {16w..} and {64+16w..}.
  short8 B1f[2][8];
  for (int p = 0; p < 2; ++p) {
    const int n = 16 * (w + 4 * p) + col;                     // 0..127
    const float* src = (p == 0) ? (W1 + n) : (A1 + (n - 64));
    for (int kt = 0; kt < 8; ++kt) {
      short8 f;
      for (int j = 0; j < 8; ++j)
        f[j] = f2bf(src[(kt * 32 + quad * 8 + j) * 64]);
      B1f[p][kt] = f;
    }
  }
  // Layer2: Wcat2 = [W2 | A2] (K=64, N=64). Wave w owns col pair {16*(w&1), 32+16*(w&1)}.
  short8 B2f[2][2];
  for (int p = 0; p < 2; ++p) {
    const int n = 16 * ((w & 1) + 2 * p) + col;               // 0..63
    const float* src = (p == 0) ? (W2 + n) : (A2 + (n - 32));
    for (int kt = 0; kt < 2; ++kt) {
      short8 f;
      for (int j = 0; j < 8; ++j)
        f[j] = f2bf(src[(kt * 32 + quad * 8 + j) * 32]);
      B2f[p][kt] = f;
    }
  }
  // Layer3: Wcat3 = [W3 | A3] (K=32, N=32). All waves own col pair {0,16}.
  short8 B3f[2];
  for (int p = 0; p < 2; ++p) {
    const int n = 16 * p + col;                               // 0..31
    const float* src = (p == 0) ? (W3 + n) : (A3 + (n - 16));
    short8 f;
    for (int j = 0; j < 8; ++j)
      f[j] = f2bf(src[(quad * 8 + j) * 16]);
    B3f[p] = f;
  }
  const float b1v = b1[16 * w + col];
  const float b2v = b2[16 * (w & 1) + col];
  const float b3v = b3[col];
  const float bfv = bfp[0];
  const float Wfv = Wf[col];
  const f32x4 zero = {0.f, 0.f, 0.f, 0.f};

  for (int tile = blockIdx.x; tile < NTILES; tile += gridDim.x) {
    const int e0 = tile * ETILE;

    // ---- gather: wave w owns half-rows h = w*32 + it*4 + quad (it 0..7).
    // 16 lanes (quad-group) read one 512B fp32 row cooperatively (32B/lane).
    // Two batches of 4 keep nd[]+transients small (low VGPR peak: no scratch).
    for (int b = 0; b < 2; ++b) {
      int nd[4];
#pragma unroll
      for (int it = 0; it < 4; ++it) {
        const int h = w * 32 + (b * 4 + it) * 4 + quad;
        nd[it] = ei[(h & 1) * E_TOTAL + e0 + (h >> 1)];   // 16-lane broadcast, L2-hot
      }
#pragma unroll
      for (int it = 0; it < 4; ++it) {
        const int h = w * 32 + (b * 4 + it) * 4 + quad;
        const float4* s4 = ((const float4*)(x + (size_t)nd[it] * FD)) + col * 2;
        float4 va = s4[0];
        float4 vb = s4[1];
        short8 s;
        s[0] = f2bf(va.x); s[1] = f2bf(va.y); s[2] = f2bf(va.z); s[3] = f2bf(va.w);
        s[4] = f2bf(vb.x); s[5] = f2bf(vb.y); s[6] = f2bf(vb.z); s[7] = f2bf(vb.w);
        *(short8*)&H0[h0idx(h >> 1, (h & 1) * 128 + col * 8)] = s;
      }
    }
    __syncthreads();                                 // B1: H0 ready

    // ---- layer 1: [64x256] @ [256x128], wave w -> all M, col pair {w, w+4} ----
    for (int mt = 0; mt < 4; ++mt) {
      f32x4 a0 = zero, a1 = zero;
      for (int kt = 0; kt < 8; ++kt) {
        short8 a = *(const short8*)&H0[h0idx(mt * 16 + col, kt * 32 + quad * 8)];
        a0 = __builtin_amdgcn_mfma_f32_16x16x32_bf16(a, B1f[0][kt], a0, 0, 0, 0);
        a1 = __builtin_amdgcn_mfma_f32_16x16x32_bf16(a, B1f[1][kt], a1, 0, 0, 0);
      }
      for (int r = 0; r < 4; ++r) {
        float o = fmaxf(a0[r] + b1v, 0.f);          // relu(h@W1 + b1)
        float h = fmaxf(o + a1[r], 0.f);            // relu(out + h@A1)
        H12[h1idx(mt * 16 + quad * 4 + r, 16 * w + col)] = f2bf(h);
      }
    }
    __syncthreads();                                 // B2: H1 ready

    // ---- layer 2 compute: [64x64] @ [64x64], waves split M in halves ----
    f32x4 c2w[2], c2a[2];
    c2w[0] = zero; c2w[1] = zero; c2a[0] = zero; c2a[1] = zero;
    for (int mi = 0; mi < 2; ++mi) {
      const int m = (2 * (w >> 1) + mi) * 16 + col;
      for (int kt = 0; kt < 2; ++kt) {
        short8 a = *(const short8*)&H12[h1idx(m, kt * 32 + quad * 8)];
        c2w[mi] = __builtin_amdgcn_mfma_f32_16x16x32_bf16(a, B2f[0][kt], c2w[mi], 0, 0, 0);
        c2a[mi] = __builtin_amdgcn_mfma_f32_16x16x32_bf16(a, B2f[1][kt], c2a[mi], 0, 0, 0);
      }
    }
    __syncthreads();                                 // B3: all H1 reads done (union hazard)

    // ---- layer 2 writeback: H2 ([64][40] padded) overlays H1's buffer ----
    for (int mi = 0; mi < 2; ++mi)
      for (int r = 0; r < 4; ++r) {
        float o = fmaxf(c2w[mi][r] + b2v, 0.f);
        float h = fmaxf(o + c2a[mi][r], 0.f);
        H12[((2 * (w >> 1) + mi) * 16 + quad * 4 + r) * 40 + 16 * (w & 1) + col] = f2bf(h);
      }
    __syncthreads();                                 // B4: H2 ready

    // ---- layer 3: [64x32] @ [32x32], wave w -> M-tile w ----
    f32x4 acc3[2];
    acc3[0] = zero; acc3[1] = zero;
    {
      short8 a = *(const short8*)&H12[(w * 16 + col) * 40 + quad * 8];
      acc3[0] = __builtin_amdgcn_mfma_f32_16x16x32_bf16(a, B3f[0], acc3[0], 0, 0, 0);
      acc3[1] = __builtin_amdgcn_mfma_f32_16x16x32_bf16(a, B3f[1], acc3[1], 0, 0, 0);
    }

    // ---- final: 16-dot via width-16 shfl butterfly, sigmoid, store ----
    // lane (quad,col) reg r holds h3[edge = w*16 + quad*4 + r][feature col]
#pragma unroll
    for (int r = 0; r < 4; ++r) {
      float o = fmaxf(acc3[0][r] + b3v, 0.f);
      float h = fmaxf(o + acc3[1][r], 0.f);
      float t = h * Wfv;
      t += __shfl_xor(t, 1, 16);
      t += __shfl_xor(t, 2, 16);
      t += __shfl_xor(t, 4, 16);
      t += __shfl_xor(t, 8, 16);
      if (col == r) {
        float s = bfv + t;
        out[e0 + w * 16 + quad * 4 + r] = 1.0f / (1.0f + __expf(-s));
      }
    }
    // loop hazard audit: next-iter gather writes H0 — every wave passed B2 (last
    // H0 reads are in layer 1, before B2). Next-iter H1 writes sit behind next B1;
    // this iter's H12 reads (layer 3) complete before that barrier. Safe.
  }
}

extern "C" void kernel_launch(void* const* d_in, const int* in_sizes, int n_in,
                              void* d_out, int out_size, void* d_ws, size_t ws_size,
                              hipStream_t stream) {
  const float* x   = (const float*)d_in[0];
  const int*   ei  = (const int*)d_in[1];
  const float* W1  = (const float*)d_in[2];
  const float* b1  = (const float*)d_in[3];
  const float* A1  = (const float*)d_in[4];
  const float* W2  = (const float*)d_in[5];
  const float* b2  = (const float*)d_in[6];
  const float* A2  = (const float*)d_in[7];
  const float* W3  = (const float*)d_in[8];
  const float* b3  = (const float*)d_in[9];
  const float* A3  = (const float*)d_in[10];
  const float* Wf  = (const float*)d_in[11];
  const float* bfp = (const float*)d_in[12];

  hipLaunchKernelGGL(linkpred_kernel, dim3(GRID), dim3(256), 0, stream,
                     x, ei, W1, b1, A1, W2, b2, A2, W3, b3, A3, Wf, bfp,
                     (float*)d_out);
}

// Round 9
// 252.747 us; speedup vs baseline: 1.4904x; 1.0798x over previous
//
#include <hip/hip_runtime.h>
#include <stdint.h>
#include <stddef.h>

#define E_TOTAL 1000000
#define N_NODES 100000
#define FD      128
#define ETILE   64
#define NTILES  (E_TOTAL / ETILE)   // 15625 exactly
#define GRID    2048

typedef __attribute__((ext_vector_type(8))) short short8;
typedef __attribute__((ext_vector_type(4))) short short4v;
typedef __attribute__((ext_vector_type(4))) float f32x4;

// round-to-nearest-even fp32 -> bf16 (bit pattern in a short)
__device__ __forceinline__ short f2bf(float f) {
  union { float f; unsigned u; } v; v.f = f;
  unsigned r = (v.u + 0x7FFFu + ((v.u >> 16) & 1u)) >> 16;
  return (short)(r & 0xFFFFu);
}

// XOR-swizzled index helpers (short-granular; byte-swizzle bits 4-6 == short bits 3-5).
// The XOR touches only short-bits 3-5, so any access whose span stays inside one
// 8-short chunk (16B stores, or 8B stores at c%8 in {0,4}) maps consistently.
__device__ __forceinline__ int h0idx(int row, int c) {
  return row * 256 + (c ^ ((row & 7) << 3));
}
// H1: logical [64][64] bf16. slot = (row>>1)&7 spreads the 128B rows across banks.
__device__ __forceinline__ int h1idx(int row, int c) {
  return row * 64 + (c ^ (((row >> 1) & 7) << 3));
}

// (256,2): (256,4) forced a 64-VGPR budget -> weight regs spilled (round 5).
// With (256,2) this body lands ~84-126 VGPR: 4 waves/EU, and LDS 40960B -> 4 blocks/CU.
__global__ __launch_bounds__(256, 2)
void linkpred_kernel(const float* __restrict__ x,
                     const int* __restrict__ ei,       // [2][E_TOTAL], int32
                     const float* __restrict__ W1, const float* __restrict__ b1,
                     const float* __restrict__ A1,
                     const float* __restrict__ W2, const float* __restrict__ b2,
                     const float* __restrict__ A2,
                     const float* __restrict__ W3, const float* __restrict__ b3,
                     const float* __restrict__ A3,
                     const float* __restrict__ Wf, const float* __restrict__ bfp,
                     float* __restrict__ out)
{
  // LDS diet for 4 blocks/CU: 32768 + 8192 = 40960 B exactly (160K/4).
  __shared__ __align__(16) short H0[ETILE * 256];   // concat(x[src],x[dst]) bf16, XOR-swizzled
  __shared__ __align__(16) short H12[ETILE * 64];   // union: H1 (swizzled [64][64]) then H2 ([64][40] padded)

  const int tid  = threadIdx.x;
  const int w    = tid >> 6;     // wave 0..3
  const int lane = tid & 63;
  const int col  = lane & 15;
  const int quad = lane >> 4;    // 0..3

  // ---------------- register-resident weight B-fragments (88 VGPRs) ----------------
  // Layer1: Wcat1 = [W1 | A1] (K=256, N=128). Wave w owns cols {16w..} and {64+16w..}.
  short8 B1f[2][8];
  for (int p = 0; p < 2; ++p) {
    const int n = 16 * (w + 4 * p) + col;                     // 0..127
    const float* src = (p == 0) ? (W1 + n) : (A1 + (n - 64));
    for (int kt = 0; kt < 8; ++kt) {
      short8 f;
      for (int j = 0; j < 8; ++j)
        f[j] = f2bf(src[(kt * 32 + quad * 8 + j) * 64]);
      B1f[p][kt] = f;
    }
  }
  // Layer2: Wcat2 = [W2 | A2] (K=64, N=64). Wave w owns col pair {16*(w&1), 32+16*(w&1)}.
  short8 B2f[2][2];
  for (int p = 0; p < 2; ++p) {
    const int n = 16 * ((w & 1) + 2 * p) + col;               // 0..63
    const float* src = (p == 0) ? (W2 + n) : (A2 + (n - 32));
    for (int kt = 0; kt < 2; ++kt) {
      short8 f;
      for (int j = 0; j < 8; ++j)
        f[j] = f2bf(src[(kt * 32 + quad * 8 + j) * 32]);
      B2f[p][kt] = f;
    }
  }
  // Layer3: Wcat3 = [W3 | A3] (K=32, N=32). All waves own col pair {0,16}.
  short8 B3f[2];
  for (int p = 0; p < 2; ++p) {
    const int n = 16 * p + col;                               // 0..31
    const float* src = (p == 0) ? (W3 + n) : (A3 + (n - 16));
    short8 f;
    for (int j = 0; j < 8; ++j)
      f[j] = f2bf(src[(quad * 8 + j) * 16]);
    B3f[p] = f;
  }
  const float b1v = b1[16 * w + col];
  const float b2v = b2[16 * (w & 1) + col];
  const float b3v = b3[col];
  const float bfv = bfp[0];
  const float Wfv = Wf[col];
  const f32x4 zero = {0.f, 0.f, 0.f, 0.f};

  const int half = lane >> 5;        // 0: src-node half, 1: dst-node half
  const int cc   = lane & 31;        // float4 index within the 128-float node row

  for (int tile = blockIdx.x; tile < NTILES; tile += gridDim.x) {
    const int e0 = tile * ETILE;

    // ---- gather (R0-style flat engine, max MLP) ----
    // Iteration it handles edge-row e = it*4 + w: lanes 0-31 read x[src] (half 0),
    // lanes 32-63 read x[dst] (half 1), one float4 (16B) per lane -> 512B/row-half,
    // fully coalesced. All 16 node indices preloaded into registers first, then 16
    // INDEPENDENT x-loads pipeline in flight (this MLP is what R2/R8's batched
    // engine destroyed: 3.07 -> 2.45 TB/s delivered).
    int nd[16];
#pragma unroll
    for (int it = 0; it < 16; ++it)
      nd[it] = ei[half * E_TOTAL + e0 + it * 4 + w];     // 32-lane broadcast loads
#pragma unroll
    for (int it = 0; it < 16; ++it) {
      const int e = it * 4 + w;
      const float4 v = ((const float4*)(x + (size_t)nd[it] * FD))[cc];
      short4v s4;
      s4[0] = f2bf(v.x); s4[1] = f2bf(v.y); s4[2] = f2bf(v.z); s4[3] = f2bf(v.w);
      *(short4v*)&H0[h0idx(e, half * 128 + cc * 4)] = s4;   // 8B store, chunk-safe
    }
    __syncthreads();                                 // B1: H0 ready

    // ---- layer 1: [64x256] @ [256x128], wave w -> all M, col pair {w, w+4} ----
    for (int mt = 0; mt < 4; ++mt) {
      f32x4 a0 = zero, a1 = zero;
      for (int kt = 0; kt < 8; ++kt) {
        short8 a = *(const short8*)&H0[h0idx(mt * 16 + col, kt * 32 + quad * 8)];
        a0 = __builtin_amdgcn_mfma_f32_16x16x32_bf16(a, B1f[0][kt], a0, 0, 0, 0);
        a1 = __builtin_amdgcn_mfma_f32_16x16x32_bf16(a, B1f[1][kt], a1, 0, 0, 0);
      }
      for (int r = 0; r < 4; ++r) {
        float o = fmaxf(a0[r] + b1v, 0.f);          // relu(h@W1 + b1)
        float h = fmaxf(o + a1[r], 0.f);            // relu(out + h@A1)
        H12[h1idx(mt * 16 + quad * 4 + r, 16 * w + col)] = f2bf(h);
      }
    }
    __syncthreads();                                 // B2: H1 ready

    // ---- layer 2 compute: [64x64] @ [64x64], waves split M in halves ----
    f32x4 c2w[2], c2a[2];
    c2w[0] = zero; c2w[1] = zero; c2a[0] = zero; c2a[1] = zero;
    for (int mi = 0; mi < 2; ++mi) {
      const int m = (2 * (w >> 1) + mi) * 16 + col;
      for (int kt = 0; kt < 2; ++kt) {
        short8 a = *(const short8*)&H12[h1idx(m, kt * 32 + quad * 8)];
        c2w[mi] = __builtin_amdgcn_mfma_f32_16x16x32_bf16(a, B2f[0][kt], c2w[mi], 0, 0, 0);
        c2a[mi] = __builtin_amdgcn_mfma_f32_16x16x32_bf16(a, B2f[1][kt], c2a[mi], 0, 0, 0);
      }
    }
    __syncthreads();                                 // B3: all H1 reads done (union hazard)

    // ---- layer 2 writeback: H2 ([64][40] padded) overlays H1's buffer ----
    for (int mi = 0; mi < 2; ++mi)
      for (int r = 0; r < 4; ++r) {
        float o = fmaxf(c2w[mi][r] + b2v, 0.f);
        float h = fmaxf(o + c2a[mi][r], 0.f);
        H12[((2 * (w >> 1) + mi) * 16 + quad * 4 + r) * 40 + 16 * (w & 1) + col] = f2bf(h);
      }
    __syncthreads();                                 // B4: H2 ready

    // ---- layer 3: [64x32] @ [32x32], wave w -> M-tile w ----
    f32x4 acc3[2];
    acc3[0] = zero; acc3[1] = zero;
    {
      short8 a = *(const short8*)&H12[(w * 16 + col) * 40 + quad * 8];
      acc3[0] = __builtin_amdgcn_mfma_f32_16x16x32_bf16(a, B3f[0], acc3[0], 0, 0, 0);
      acc3[1] = __builtin_amdgcn_mfma_f32_16x16x32_bf16(a, B3f[1], acc3[1], 0, 0, 0);
    }

    // ---- final: 16-dot via width-16 shfl butterfly, sigmoid, store ----
    // lane (quad,col) reg r holds h3[edge = w*16 + quad*4 + r][feature col]
#pragma unroll
    for (int r = 0; r < 4; ++r) {
      float o = fmaxf(acc3[0][r] + b3v, 0.f);
      float h = fmaxf(o + acc3[1][r], 0.f);
      float t = h * Wfv;
      t += __shfl_xor(t, 1, 16);
      t += __shfl_xor(t, 2, 16);
      t += __shfl_xor(t, 4, 16);
      t += __shfl_xor(t, 8, 16);
      if (col == r) {
        float s = bfv + t;
        out[e0 + w * 16 + quad * 4 + r] = 1.0f / (1.0f + __expf(-s));
      }
    }
    // loop hazard audit: next-iter gather writes H0 — every wave passed B2 (last
    // H0 reads are in layer 1, before B2). Next-iter H1 writes sit behind next B1;
    // this iter's H12 reads (layer 3) complete before that barrier. Safe.
  }
}

extern "C" void kernel_launch(void* const* d_in, const int* in_sizes, int n_in,
                              void* d_out, int out_size, void* d_ws, size_t ws_size,
                              hipStream_t stream) {
  const float* x   = (const float*)d_in[0];
  const int*   ei  = (const int*)d_in[1];
  const float* W1  = (const float*)d_in[2];
  const float* b1  = (const float*)d_in[3];
  const float* A1  = (const float*)d_in[4];
  const float* W2  = (const float*)d_in[5];
  const float* b2  = (const float*)d_in[6];
  const float* A2  = (const float*)d_in[7];
  const float* W3  = (const float*)d_in[8];
  const float* b3  = (const float*)d_in[9];
  const float* A3  = (const float*)d_in[10];
  const float* Wf  = (const float*)d_in[11];
  const float* bfp = (const float*)d_in[12];

  hipLaunchKernelGGL(linkpred_kernel, dim3(GRID), dim3(256), 0, stream,
                     x, ei, W1, b1, A1, W2, b2, A2, W3, b3, A3, Wf, bfp,
                     (float*)d_out);
}